// Round 13
// baseline (491.718 us; speedup 1.0000x reference)
//
#include <hip/hip_runtime.h>
#include <hip/hip_bf16.h>
#include <stdint.h>

#define D 128
#define H 8
#define DK 16

#define SCAN_BLK 256
#define SCAN_ITEMS 8
#define SCAN_TILE (SCAN_BLK * SCAN_ITEMS)

typedef __attribute__((ext_vector_type(8))) short bf16x8;
typedef __attribute__((ext_vector_type(4))) float f32x4;

// ---------- bf16 helpers ----------
__device__ __forceinline__ unsigned short f2bf(float f) {
    unsigned int u = __float_as_uint(f);
    u = u + 0x7fffu + ((u >> 16) & 1u);      // round-to-nearest-even
    return (unsigned short)(u >> 16);
}
__device__ __forceinline__ float bfl(unsigned int u) { return __uint_as_float(u << 16); }
__device__ __forceinline__ float bfh(unsigned int u) { return __uint_as_float(u & 0xffff0000u); }
__device__ __forceinline__ unsigned int pack2(unsigned short a, unsigned short b) {
    return (unsigned int)a | ((unsigned int)b << 16);
}
__device__ __forceinline__ void unpack8(uint4 u, float* o) {
    o[0]=bfl(u.x); o[1]=bfh(u.x); o[2]=bfl(u.y); o[3]=bfh(u.y);
    o[4]=bfl(u.z); o[5]=bfh(u.z); o[6]=bfl(u.w); o[7]=bfh(u.w);
}

// ---------- combined prep: W^T transposes + relation folds + cnt zeroing ----------
struct WTIn  { const float* w[4]; };
struct WTOut { unsigned short* wt[4]; };
struct FoldArgs {
    const float* W[6]; const float* R[6]; const float* b[6];
    unsigned short* WT[6]; float* bf[6]; int mode[6];
};

__global__ __launch_bounds__(256) void prep_kernel(WTIn in, WTOut out, FoldArgs a,
                                                   int* __restrict__ cnt, int S) {
    __shared__ float tile[32][33];
    __shared__ float Wl[128 * 17];
    __shared__ float Rl[256];
    int bid = blockIdx.x;
    int tid = threadIdx.x;
    if (bid < 64) {
        int mat = bid >> 4;
        int t = bid & 15;
        int k0 = (t >> 2) * 32, c0 = (t & 3) * 32;
        const float* W = in.w[mat];
        unsigned short* WT = out.wt[mat];
        int lr = tid >> 5, lc = tid & 31;
        #pragma unroll
        for (int p = 0; p < 4; ++p)
            tile[p * 8 + lr][lc] = W[(size_t)(k0 + p * 8 + lr) * D + c0 + lc];
        __syncthreads();
        #pragma unroll
        for (int p = 0; p < 4; ++p)
            WT[(size_t)(c0 + p * 8 + lr) * D + k0 + lc] = f2bf(tile[lc][p * 8 + lr]);
    } else if (bid < 112) {
        int v = (bid - 64) >> 3, h = (bid - 64) & 7;
        const float* W = a.W[v];
        #pragma unroll
        for (int p = 0; p < 8; ++p) {
            int idx = p * 256 + tid;
            int c = idx >> 4, i = idx & 15;
            Wl[c * 17 + i] = W[(size_t)c * D + h * 16 + i];
        }
        Rl[tid] = a.R[v][h * 256 + tid];
        __syncthreads();
        int mode = a.mode[v];
        int c = tid & 127, jb = (tid >> 7) * 8;
        #pragma unroll
        for (int jj = 0; jj < 8; ++jj) {
            int j = jb + jj;
            float s = 0.f;
            #pragma unroll
            for (int i = 0; i < 16; ++i)
                s = fmaf(Wl[c * 17 + i], mode ? Rl[i * 16 + j] : Rl[j * 16 + i], s);
            a.WT[v][(size_t)(h * 16 + j) * D + c] = f2bf(s);
        }
        if (tid < 16) {
            const float* b = a.b[v];
            float s = 0.f;
            #pragma unroll
            for (int i = 0; i < 16; ++i)
                s = fmaf(b[h * 16 + i], mode ? Rl[i * 16 + tid] : Rl[tid * 16 + i], s);
            a.bf[v][h * 16 + tid] = s;
        }
    } else {
        int base = (bid - 112) * 1024 + tid * 4;
        if (base + 4 <= S) {
            *(int4*)&cnt[base] = make_int4(0, 0, 0, 0);
        } else {
            for (int i = base; i < S; ++i) cnt[i] = 0;
        }
    }
}

// ---------- fused MFMA multi-output projection, both node types in one launch ----------
#define ASTRIDE 136
struct ProjFusedArgs {
    const float* X[2];
    int N[2], nmat[2], nblk0;
    const unsigned short* wt[2][5];
    const float* bias[2][5];
    unsigned short* out[2][5];
};

__global__ __launch_bounds__(256) void proj_fused_kernel(ProjFusedArgs a)
{
    __shared__ unsigned short As[64 * ASTRIDE];
    __shared__ unsigned short Cs[64 * ASTRIDE];
    const int tid = threadIdx.x;
    const int w = tid >> 6;
    const int l = tid & 63;
    const int seg = (blockIdx.x >= a.nblk0) ? 1 : 0;
    const int row0 = (blockIdx.x - (seg ? a.nblk0 : 0)) * 64;
    const float* X = a.X[seg];
    const int N = a.N[seg];
    const int nm = a.nmat[seg];

    #pragma unroll
    for (int p = 0; p < 8; ++p) {
        int f = p * 256 + tid;
        int r = f >> 5;
        int c4 = f & 31;
        int row = row0 + r; if (row >= N) row = N - 1;
        float4 xv = *(const float4*)&X[(size_t)row * D + c4 * 4];
        unsigned int lo = pack2(f2bf(xv.x), f2bf(xv.y));
        unsigned int hi = pack2(f2bf(xv.z), f2bf(xv.w));
        *(uint2*)&As[r * ASTRIDE + c4 * 4] = make_uint2(lo, hi);
    }
    __syncthreads();

    const int lrow = l & 15;
    const int lk8 = (l >> 4) * 8;

    for (int m = 0; m < nm; ++m) {
        const unsigned short* WT = a.wt[seg][m];
        bf16x8 bfrag[2][4];
        #pragma unroll
        for (int cf = 0; cf < 2; ++cf)
            #pragma unroll
            for (int kc = 0; kc < 4; ++kc)
                bfrag[cf][kc] = *(const bf16x8*)&WT[(size_t)(w * 32 + cf * 16 + lrow) * D + kc * 32 + lk8];

        f32x4 acc[4][2];
        #pragma unroll
        for (int rf = 0; rf < 4; ++rf) {
            acc[rf][0] = (f32x4){0.f, 0.f, 0.f, 0.f};
            acc[rf][1] = (f32x4){0.f, 0.f, 0.f, 0.f};
        }
        #pragma unroll
        for (int rf = 0; rf < 4; ++rf) {
            bf16x8 afrag[4];
            #pragma unroll
            for (int kc = 0; kc < 4; ++kc)
                afrag[kc] = *(const bf16x8*)&As[(rf * 16 + lrow) * ASTRIDE + kc * 32 + lk8];
            #pragma unroll
            for (int kc = 0; kc < 4; ++kc) {
                acc[rf][0] = __builtin_amdgcn_mfma_f32_16x16x32_bf16(afrag[kc], bfrag[0][kc], acc[rf][0], 0, 0, 0);
                acc[rf][1] = __builtin_amdgcn_mfma_f32_16x16x32_bf16(afrag[kc], bfrag[1][kc], acc[rf][1], 0, 0, 0);
            }
        }
        float bias0 = a.bias[seg][m][w * 32 + lrow];
        float bias1 = a.bias[seg][m][w * 32 + 16 + lrow];
        #pragma unroll
        for (int rf = 0; rf < 4; ++rf) {
            #pragma unroll
            for (int r = 0; r < 4; ++r) {
                int lr = rf * 16 + (l >> 4) * 4 + r;
                Cs[lr * ASTRIDE + w * 32 + lrow]      = f2bf(acc[rf][0][r] + bias0);
                Cs[lr * ASTRIDE + w * 32 + 16 + lrow] = f2bf(acc[rf][1][r] + bias1);
            }
        }
        __syncthreads();
        unsigned short* O = a.out[seg][m];
        #pragma unroll
        for (int p = 0; p < 4; ++p) {
            int idx = p * 256 + tid;
            int r = idx >> 4, c8 = idx & 15;
            int row = row0 + r;
            if (row < N)
                *(uint4*)&O[(size_t)row * D + c8 * 8] = *(const uint4*)&Cs[r * ASTRIDE + c8 * 8];
        }
        __syncthreads();
    }
}

// ---------- fused MFMA out-GEMM (both node types) ----------
struct OutFusedArgs {
    const unsigned short* T1[2]; const unsigned short* T2[2];
    const unsigned short* WT[2]; const float* bias[2];
    const float* skip[2]; const float* X[2]; float* O[2];
    int N[2], nsrc[2], nblk0;
};

__global__ __launch_bounds__(256) void out_fused_kernel(OutFusedArgs a)
{
    __shared__ unsigned short As[64 * ASTRIDE];
    const int tid = threadIdx.x;
    const int w = tid >> 6;
    const int l = tid & 63;
    const int seg = (blockIdx.x >= a.nblk0) ? 1 : 0;
    const int row0 = (blockIdx.x - (seg ? a.nblk0 : 0)) * 64;
    const int N = a.N[seg];
    const int nsrc = a.nsrc[seg];
    const unsigned short* T1 = a.T1[seg];
    const unsigned short* T2 = a.T2[seg];

    #pragma unroll
    for (int p = 0; p < 4; ++p) {
        int idx = p * 256 + tid;
        int r = idx >> 4;
        int c8 = idx & 15;
        int row = row0 + r; if (row >= N) row = N - 1;
        uint4 tv = *(const uint4*)&T1[(size_t)row * D + c8 * 8];
        float v[8]; unpack8(tv, v);
        #pragma unroll
        for (int i = 0; i < 8; ++i) v[i] = fmaxf(v[i], 0.f);
        if (nsrc == 2) {
            uint4 uv = *(const uint4*)&T2[(size_t)row * D + c8 * 8];
            float u[8]; unpack8(uv, u);
            #pragma unroll
            for (int i = 0; i < 8; ++i) v[i] = 0.5f * (v[i] + fmaxf(u[i], 0.f));
        }
        uint4 pk;
        pk.x = pack2(f2bf(v[0]), f2bf(v[1]));
        pk.y = pack2(f2bf(v[2]), f2bf(v[3]));
        pk.z = pack2(f2bf(v[4]), f2bf(v[5]));
        pk.w = pack2(f2bf(v[6]), f2bf(v[7]));
        *(uint4*)&As[r * ASTRIDE + c8 * 8] = pk;
    }
    __syncthreads();

    const int lrow = l & 15;
    const int lk8 = (l >> 4) * 8;
    const unsigned short* WT = a.WT[seg];

    bf16x8 bfrag[2][4];
    #pragma unroll
    for (int cf = 0; cf < 2; ++cf)
        #pragma unroll
        for (int kc = 0; kc < 4; ++kc)
            bfrag[cf][kc] = *(const bf16x8*)&WT[(size_t)(w * 32 + cf * 16 + lrow) * D + kc * 32 + lk8];

    f32x4 acc[4][2];
    #pragma unroll
    for (int rf = 0; rf < 4; ++rf) {
        acc[rf][0] = (f32x4){0.f, 0.f, 0.f, 0.f};
        acc[rf][1] = (f32x4){0.f, 0.f, 0.f, 0.f};
    }
    #pragma unroll
    for (int rf = 0; rf < 4; ++rf) {
        bf16x8 afrag[4];
        #pragma unroll
        for (int kc = 0; kc < 4; ++kc)
            afrag[kc] = *(const bf16x8*)&As[(rf * 16 + lrow) * ASTRIDE + kc * 32 + lk8];
        #pragma unroll
        for (int kc = 0; kc < 4; ++kc) {
            acc[rf][0] = __builtin_amdgcn_mfma_f32_16x16x32_bf16(afrag[kc], bfrag[0][kc], acc[rf][0], 0, 0, 0);
            acc[rf][1] = __builtin_amdgcn_mfma_f32_16x16x32_bf16(afrag[kc], bfrag[1][kc], acc[rf][1], 0, 0, 0);
        }
    }
    float alpha = 1.f / (1.f + __expf(-a.skip[seg][0]));
    float om = 1.f - alpha;
    float bias0 = a.bias[seg][w * 32 + lrow];
    float bias1 = a.bias[seg][w * 32 + 16 + lrow];
    const float* X = a.X[seg];
    float* O = a.O[seg];
    #pragma unroll
    for (int rf = 0; rf < 4; ++rf) {
        #pragma unroll
        for (int r = 0; r < 4; ++r) {
            int row = row0 + rf * 16 + (l >> 4) * 4 + r;
            if (row < N) {
                int c0 = w * 32 + lrow;
                float x0 = X[(size_t)row * D + c0];
                float x1 = X[(size_t)row * D + c0 + 16];
                O[(size_t)row * D + c0]      = (acc[rf][0][r] + bias0) * alpha + x0 * om;
                O[(size_t)row * D + c0 + 16] = (acc[rf][1][r] + bias1) * alpha + x1 * om;
            }
        }
    }
}

// ---------- combined CSR build over 3 etypes in slot space ----------
struct EdgeArgs {
    const int* src[3]; const int* dst[3]; int base[3]; int E;
};

// hist, 4 edges/thread; records each edge's rank within its dst segment
__global__ __launch_bounds__(256) void hist_all_kernel(EdgeArgs a, int* __restrict__ cnt,
                                                       int* __restrict__ rank) {
    int E = a.E;
    int perE = (E + 3) >> 2;                 // vec4 threads per etype
    int gid = blockIdx.x * 256 + threadIdx.x;
    int t = gid / perE;
    if (t >= 3) return;
    int e4 = (gid - t * perE) * 4;
    const int* dstp = a.dst[t];
    int b = a.base[t];
    if (e4 + 4 <= E) {
        int4 d = *(const int4*)&dstp[e4];
        int4 r;
        r.x = atomicAdd(&cnt[b + d.x], 1);
        r.y = atomicAdd(&cnt[b + d.y], 1);
        r.z = atomicAdd(&cnt[b + d.z], 1);
        r.w = atomicAdd(&cnt[b + d.w], 1);
        *(int4*)&rank[t * E + e4] = r;
    } else {
        for (int e = e4; e < E; ++e)
            rank[t * E + e] = atomicAdd(&cnt[b + dstp[e]], 1);
    }
}

// single-pass scan: each block computes its global prefix directly from cnt,
// then scans its own tile and writes offs. (replaces scan1+scan3; no bsum)
__global__ __launch_bounds__(SCAN_BLK) void scan_kernel(
    const int* __restrict__ cnt, int* __restrict__ offs, int n)
{
    __shared__ int red[SCAN_BLK];
    __shared__ int sh[SCAN_BLK];
    const int tid = threadIdx.x;
    const int lim = blockIdx.x * SCAN_TILE;
    int pre = 0;
    for (int i = tid; i < lim; i += SCAN_BLK) pre += cnt[i];
    red[tid] = pre; __syncthreads();
    for (int o = SCAN_BLK / 2; o > 0; o >>= 1) {
        if (tid < o) red[tid] += red[tid + o];
        __syncthreads();
    }
    int base0 = red[0];

    int base = lim + tid * SCAN_ITEMS;
    int v[SCAN_ITEMS];
    int s = 0;
    #pragma unroll
    for (int i = 0; i < SCAN_ITEMS; ++i) {
        int idx = base + i;
        v[i] = (idx < n) ? cnt[idx] : 0;
        s += v[i];
    }
    sh[tid] = s; __syncthreads();
    for (int o = 1; o < SCAN_BLK; o <<= 1) {
        int t = (tid >= o) ? sh[tid - o] : 0;
        __syncthreads();
        sh[tid] += t;
        __syncthreads();
    }
    int off = base0 + sh[tid] - s;
    #pragma unroll
    for (int i = 0; i < SCAN_ITEMS; ++i) {
        int idx = base + i;
        if (idx < n) {
            offs[idx] = off;
            off += v[i];
            if (idx == n - 1) offs[n] = off;
        }
    }
}

// atomic-free scatter, 4 edges/thread: position = offs[dst] + rank
__global__ __launch_bounds__(256) void scatter_all_kernel(
    EdgeArgs a, const int* __restrict__ offs, const int* __restrict__ rank,
    int* __restrict__ csr_src)
{
    int E = a.E;
    int perE = (E + 3) >> 2;
    int gid = blockIdx.x * 256 + threadIdx.x;
    int t = gid / perE;
    if (t >= 3) return;
    int e4 = (gid - t * perE) * 4;
    const int* dstp = a.dst[t];
    const int* srcp = a.src[t];
    int b = a.base[t];
    if (e4 + 4 <= E) {
        int4 d = *(const int4*)&dstp[e4];
        int4 r = *(const int4*)&rank[t * E + e4];
        int4 s = *(const int4*)&srcp[e4];
        csr_src[offs[b + d.x] + r.x] = s.x;
        csr_src[offs[b + d.y] + r.y] = s.y;
        csr_src[offs[b + d.z] + r.z] = s.z;
        csr_src[offs[b + d.w] + r.w] = s.w;
    } else {
        for (int e = e4; e < E; ++e)
            csr_src[offs[b + dstp[e]] + rank[t * E + e]] = srcp[e];
    }
}

// ---------- fused per-dst softmax + aggregate, 2 lanes per (slot,head), 2-edge unroll ----------
struct AggArgs {
    const unsigned short* K[3];
    const unsigned short* Q[3];
    const unsigned short* V[3];
    const float* pri[3];
    unsigned short* T[3];
};

__global__ __launch_bounds__(256) void csr_agg_all_kernel(
    const int* __restrict__ offs, const int* __restrict__ csr_src,
    AggArgs a, int n_b, int n_a)
{
    int gid = blockIdx.x * 256 + threadIdx.x;
    int si = gid >> 4;
    int hp = gid & 15;
    int h = hp >> 1, p = hp & 1;
    int S = 2 * n_b + n_a;
    if (si >= S) return;
    int s = si;
    int t = (s < n_b) ? 0 : ((s < 2 * n_b) ? 1 : 2);
    int n = s - ((t == 2) ? 2 * n_b : t * n_b);

    const unsigned short *Kp, *Qp, *Vp; const float* prip; unsigned short* Tp;
    if (t == 0)      { Kp=a.K[0]; Qp=a.Q[0]; Vp=a.V[0]; prip=a.pri[0]; Tp=a.T[0]; }
    else if (t == 1) { Kp=a.K[1]; Qp=a.Q[1]; Vp=a.V[1]; prip=a.pri[1]; Tp=a.T[1]; }
    else             { Kp=a.K[2]; Qp=a.Q[2]; Vp=a.V[2]; prip=a.pri[2]; Tp=a.T[2]; }

    int e0 = offs[s], e1 = offs[s + 1];
    const int sub = h * DK + p * 8;

    uint4 q = *(const uint4*)(Qp + (size_t)n * D + sub);
    float qv[8]; unpack8(q, qv);
    float ps = prip[h] * 0.25f;

    float acc[8];
    #pragma unroll
    for (int i = 0; i < 8; ++i) acc[i] = 0.f;
    float den = 0.f;

    int e = e0;
    for (; e + 2 <= e1; e += 2) {
        int s0 = csr_src[e], s1 = csr_src[e + 1];
        uint4 k0 = *(const uint4*)(Kp + (size_t)s0 * D + sub);
        uint4 v0 = *(const uint4*)(Vp + (size_t)s0 * D + sub);
        uint4 k1 = *(const uint4*)(Kp + (size_t)s1 * D + sub);
        uint4 v1 = *(const uint4*)(Vp + (size_t)s1 * D + sub);
        float ka[8], kb[8];
        unpack8(k0, ka); unpack8(k1, kb);
        float d0 = 0.f, d1 = 0.f;
        #pragma unroll
        for (int i = 0; i < 8; ++i) {
            d0 = fmaf(ka[i], qv[i], d0);
            d1 = fmaf(kb[i], qv[i], d1);
        }
        d0 += __shfl_xor(d0, 1, 64);
        d1 += __shfl_xor(d1, 1, 64);
        float ea0 = __expf(d0 * ps);
        float ea1 = __expf(d1 * ps);
        den += ea0 + ea1;
        float va[8], vb[8];
        unpack8(v0, va); unpack8(v1, vb);
        #pragma unroll
        for (int i = 0; i < 8; ++i)
            acc[i] = fmaf(ea0, va[i], fmaf(ea1, vb[i], acc[i]));
    }
    if (e < e1) {
        int s0 = csr_src[e];
        uint4 k = *(const uint4*)(Kp + (size_t)s0 * D + sub);
        uint4 v = *(const uint4*)(Vp + (size_t)s0 * D + sub);
        float kv[8]; unpack8(k, kv);
        float d = 0.f;
        #pragma unroll
        for (int i = 0; i < 8; ++i) d = fmaf(kv[i], qv[i], d);
        d += __shfl_xor(d, 1, 64);
        float ea = __expf(d * ps);
        den += ea;
        float vv[8]; unpack8(v, vv);
        #pragma unroll
        for (int i = 0; i < 8; ++i) acc[i] = fmaf(ea, vv[i], acc[i]);
    }
    float inv = 1.f / fmaxf(den, 1e-9f);
    unsigned short ob[8];
    #pragma unroll
    for (int i = 0; i < 8; ++i) ob[i] = f2bf(acc[i] * inv);
    uint4 o0;
    o0.x = pack2(ob[0], ob[1]);  o0.y = pack2(ob[2], ob[3]);
    o0.z = pack2(ob[4], ob[5]);  o0.w = pack2(ob[6], ob[7]);
    *(uint4*)(Tp + (size_t)n * D + sub) = o0;
}

extern "C" void kernel_launch(void* const* d_in, const int* in_sizes, int n_in,
                              void* d_out, int out_size, void* d_ws, size_t ws_size,
                              hipStream_t stream) {
    const float* x_a = (const float*)d_in[0];
    const float* x_b = (const float*)d_in[1];
    const int* src_ab = (const int*)d_in[2];
    const int* dst_ab = (const int*)d_in[3];
    const int* src_ba = (const int*)d_in[4];
    const int* dst_ba = (const int*)d_in[5];
    const int* src_bb = (const int*)d_in[6];
    const int* dst_bb = (const int*)d_in[7];
    const float* Wk_a = (const float*)d_in[8];  const float* bk_a = (const float*)d_in[9];
    const float* Wq_a = (const float*)d_in[10]; const float* bq_a = (const float*)d_in[11];
    const float* Wv_a = (const float*)d_in[12]; const float* bv_a = (const float*)d_in[13];
    const float* Wa_a = (const float*)d_in[14]; const float* ba_a = (const float*)d_in[15];
    const float* skip_a = (const float*)d_in[16];
    const float* Wk_b = (const float*)d_in[17]; const float* bk_b = (const float*)d_in[18];
    const float* Wq_b = (const float*)d_in[19]; const float* bq_b = (const float*)d_in[20];
    const float* Wv_b = (const float*)d_in[21]; const float* bv_b = (const float*)d_in[22];
    const float* Wa_b = (const float*)d_in[23]; const float* ba_b = (const float*)d_in[24];
    const float* skip_b = (const float*)d_in[25];
    const float* pri_ab = (const float*)d_in[26];
    const float* att_ab = (const float*)d_in[27];
    const float* msg_ab = (const float*)d_in[28];
    const float* pri_ba = (const float*)d_in[29];
    const float* att_ba = (const float*)d_in[30];
    const float* msg_ba = (const float*)d_in[31];
    const float* pri_bb = (const float*)d_in[32];
    const float* att_bb = (const float*)d_in[33];
    const float* msg_bb = (const float*)d_in[34];

    const int n_a = in_sizes[0] / D;
    const int n_b = in_sizes[1] / D;
    const int E = in_sizes[2];
    const int S = 2 * n_b + n_a;

    size_t off = 0;
    char* base = (char*)d_ws;
    auto alloc = [&](size_t bytes) -> void* {
        void* r = base + off;
        off += (bytes + 255) & ~(size_t)255;
        return r;
    };
    unsigned short* k_a = (unsigned short*)alloc((size_t)n_a * D * 2);
    unsigned short* k_b = (unsigned short*)alloc((size_t)n_b * D * 2);
    unsigned short* qab = (unsigned short*)alloc((size_t)n_b * D * 2);
    unsigned short* qbb = (unsigned short*)alloc((size_t)n_b * D * 2);
    unsigned short* qba = (unsigned short*)alloc((size_t)n_a * D * 2);
    unsigned short* vab = (unsigned short*)alloc((size_t)n_a * D * 2);
    unsigned short* vbb = (unsigned short*)alloc((size_t)n_b * D * 2);
    unsigned short* vba = (unsigned short*)alloc((size_t)n_b * D * 2);
    unsigned short* t_a  = (unsigned short*)alloc((size_t)n_a * D * 2);
    unsigned short* t_b1 = (unsigned short*)alloc((size_t)n_b * D * 2);
    unsigned short* t_b2 = (unsigned short*)alloc((size_t)n_b * D * 2);
    int* cnt    = (int*)alloc((size_t)S * 4);
    int* offs   = (int*)alloc(((size_t)S + 1) * 4);
    int* rank   = (int*)alloc((size_t)3 * E * 4);
    int* csr_src= (int*)alloc((size_t)3 * E * 4);
    unsigned short* wt_plain[4];
    for (int i = 0; i < 4; ++i) wt_plain[i] = (unsigned short*)alloc((size_t)D * D * 2);
    unsigned short* wt_fold[6];
    float* bf_fold[6];
    for (int i = 0; i < 6; ++i) {
        wt_fold[i] = (unsigned short*)alloc((size_t)D * D * 2);
        bf_fold[i] = (float*)alloc((size_t)D * 4);
    }

    // prep: transposes (Wk_a, Wk_b, Wa_a, Wa_b), folds, zero cnt
    WTIn win; WTOut wout;
    const float* worig[4] = {Wk_a, Wk_b, Wa_a, Wa_b};
    for (int i = 0; i < 4; ++i) { win.w[i] = worig[i]; wout.wt[i] = wt_plain[i]; }
    FoldArgs fa;
    const float* fW[6] = {Wq_b, Wq_b, Wq_a, Wv_a, Wv_b, Wv_b};
    const float* fR[6] = {att_ab, att_bb, att_ba, msg_ab, msg_bb, msg_ba};
    const float* fb[6] = {bq_b, bq_b, bq_a, bv_a, bv_b, bv_b};
    int fm[6] = {0, 0, 0, 1, 1, 1};
    for (int i = 0; i < 6; ++i) {
        fa.W[i] = fW[i]; fa.R[i] = fR[i]; fa.b[i] = fb[i];
        fa.WT[i] = wt_fold[i]; fa.bf[i] = bf_fold[i]; fa.mode[i] = fm[i];
    }
    int nz = (S + 1023) / 1024;
    prep_kernel<<<112 + nz, 256, 0, stream>>>(win, wout, fa, cnt, S);

    // combined CSR build (rank-in-hist, single-pass scan, atomic-free scatter)
    EdgeArgs ea;
    ea.src[0] = src_ab; ea.dst[0] = dst_ab;
    ea.src[1] = src_bb; ea.dst[1] = dst_bb;
    ea.src[2] = src_ba; ea.dst[2] = dst_ba;
    ea.base[0] = 0; ea.base[1] = n_b; ea.base[2] = 2 * n_b;
    ea.E = E;
    int perE = (E + 3) >> 2;
    int gv = (3 * perE + 255) / 256;
    hist_all_kernel<<<gv, 256, 0, stream>>>(ea, cnt, rank);
    int nb = (S + SCAN_TILE - 1) / SCAN_TILE;
    scan_kernel<<<nb, SCAN_BLK, 0, stream>>>(cnt, offs, S);
    scatter_all_kernel<<<gv, 256, 0, stream>>>(ea, offs, rank, csr_src);

    // fused projections (both node types)
    const int gb_a = (n_a + 63) / 64;
    const int gb_b = (n_b + 63) / 64;
    ProjFusedArgs pa;
    pa.X[0] = x_a; pa.N[0] = n_a; pa.nmat[0] = 3;
    pa.X[1] = x_b; pa.N[1] = n_b; pa.nmat[1] = 5;
    pa.nblk0 = gb_a;
    pa.wt[0][0] = wt_plain[0]; pa.bias[0][0] = bk_a;       pa.out[0][0] = k_a;
    pa.wt[0][1] = wt_fold[2];  pa.bias[0][1] = bf_fold[2]; pa.out[0][1] = qba;
    pa.wt[0][2] = wt_fold[3];  pa.bias[0][2] = bf_fold[3]; pa.out[0][2] = vab;
    pa.wt[0][3] = wt_plain[0]; pa.bias[0][3] = bk_a;       pa.out[0][3] = k_a;   // unused
    pa.wt[0][4] = wt_plain[0]; pa.bias[0][4] = bk_a;       pa.out[0][4] = k_a;   // unused
    pa.wt[1][0] = wt_plain[1]; pa.bias[1][0] = bk_b;       pa.out[1][0] = k_b;
    pa.wt[1][1] = wt_fold[0];  pa.bias[1][1] = bf_fold[0]; pa.out[1][1] = qab;
    pa.wt[1][2] = wt_fold[1];  pa.bias[1][2] = bf_fold[1]; pa.out[1][2] = qbb;
    pa.wt[1][3] = wt_fold[4];  pa.bias[1][3] = bf_fold[4]; pa.out[1][3] = vbb;
    pa.wt[1][4] = wt_fold[5];  pa.bias[1][4] = bf_fold[5]; pa.out[1][4] = vba;
    proj_fused_kernel<<<gb_a + gb_b, 256, 0, stream>>>(pa);

    // fused aggregate (all etypes, natural slot order, 2 lanes/head, 2-edge unroll)
    AggArgs aa;
    aa.K[0] = k_a; aa.Q[0] = qab; aa.V[0] = vab; aa.pri[0] = pri_ab; aa.T[0] = t_b1;
    aa.K[1] = k_b; aa.Q[1] = qbb; aa.V[1] = vbb; aa.pri[1] = pri_bb; aa.T[1] = t_b2;
    aa.K[2] = k_b; aa.Q[2] = qba; aa.V[2] = vba; aa.pri[2] = pri_ba; aa.T[2] = t_a;
    int gs = (S * 16 + 255) / 256;
    csr_agg_all_kernel<<<gs, 256, 0, stream>>>(offs, csr_src, aa, n_b, n_a);

    // fused final skip-connection GEMMs
    float* out_a = (float*)d_out;
    float* out_b = (float*)d_out + (size_t)n_a * D;
    OutFusedArgs oa;
    oa.T1[0] = t_a;  oa.T2[0] = t_a;  oa.WT[0] = wt_plain[2]; oa.bias[0] = ba_a;
    oa.skip[0] = skip_a; oa.X[0] = x_a; oa.O[0] = out_a; oa.N[0] = n_a; oa.nsrc[0] = 1;
    oa.T1[1] = t_b1; oa.T2[1] = t_b2; oa.WT[1] = wt_plain[3]; oa.bias[1] = ba_b;
    oa.skip[1] = skip_b; oa.X[1] = x_b; oa.O[1] = out_b; oa.N[1] = n_b; oa.nsrc[1] = 2;
    oa.nblk0 = gb_a;
    out_fused_kernel<<<gb_a + gb_b, 256, 0, stream>>>(oa);
}

// Round 14
// 349.971 us; speedup vs baseline: 1.4050x; 1.4050x over previous
//
#include <hip/hip_runtime.h>
#include <hip/hip_bf16.h>
#include <stdint.h>

#define D 128
#define H 8
#define DK 16

#define SCAN_BLK 256
#define SCAN_ITEMS 8
#define SCAN_TILE (SCAN_BLK * SCAN_ITEMS)

typedef __attribute__((ext_vector_type(8))) short bf16x8;
typedef __attribute__((ext_vector_type(4))) float f32x4;

// ---------- bf16 helpers ----------
__device__ __forceinline__ unsigned short f2bf(float f) {
    unsigned int u = __float_as_uint(f);
    u = u + 0x7fffu + ((u >> 16) & 1u);      // round-to-nearest-even
    return (unsigned short)(u >> 16);
}
__device__ __forceinline__ float bfl(unsigned int u) { return __uint_as_float(u << 16); }
__device__ __forceinline__ float bfh(unsigned int u) { return __uint_as_float(u & 0xffff0000u); }
__device__ __forceinline__ unsigned int pack2(unsigned short a, unsigned short b) {
    return (unsigned int)a | ((unsigned int)b << 16);
}
__device__ __forceinline__ void unpack8(uint4 u, float* o) {
    o[0]=bfl(u.x); o[1]=bfh(u.x); o[2]=bfl(u.y); o[3]=bfh(u.y);
    o[4]=bfl(u.z); o[5]=bfh(u.z); o[6]=bfl(u.w); o[7]=bfh(u.w);
}

// ---------- combined prep: W^T transposes + relation folds + cnt zeroing ----------
struct WTIn  { const float* w[4]; };
struct WTOut { unsigned short* wt[4]; };
struct FoldArgs {
    const float* W[6]; const float* R[6]; const float* b[6];
    unsigned short* WT[6]; float* bf[6]; int mode[6];
};

__global__ __launch_bounds__(256) void prep_kernel(WTIn in, WTOut out, FoldArgs a,
                                                   int* __restrict__ cnt, int S) {
    __shared__ float tile[32][33];
    __shared__ float Wl[128 * 17];
    __shared__ float Rl[256];
    int bid = blockIdx.x;
    int tid = threadIdx.x;
    if (bid < 64) {
        int mat = bid >> 4;
        int t = bid & 15;
        int k0 = (t >> 2) * 32, c0 = (t & 3) * 32;
        const float* W = in.w[mat];
        unsigned short* WT = out.wt[mat];
        int lr = tid >> 5, lc = tid & 31;
        #pragma unroll
        for (int p = 0; p < 4; ++p)
            tile[p * 8 + lr][lc] = W[(size_t)(k0 + p * 8 + lr) * D + c0 + lc];
        __syncthreads();
        #pragma unroll
        for (int p = 0; p < 4; ++p)
            WT[(size_t)(c0 + p * 8 + lr) * D + k0 + lc] = f2bf(tile[lc][p * 8 + lr]);
    } else if (bid < 112) {
        int v = (bid - 64) >> 3, h = (bid - 64) & 7;
        const float* W = a.W[v];
        #pragma unroll
        for (int p = 0; p < 8; ++p) {
            int idx = p * 256 + tid;
            int c = idx >> 4, i = idx & 15;
            Wl[c * 17 + i] = W[(size_t)c * D + h * 16 + i];
        }
        Rl[tid] = a.R[v][h * 256 + tid];
        __syncthreads();
        int mode = a.mode[v];
        int c = tid & 127, jb = (tid >> 7) * 8;
        #pragma unroll
        for (int jj = 0; jj < 8; ++jj) {
            int j = jb + jj;
            float s = 0.f;
            #pragma unroll
            for (int i = 0; i < 16; ++i)
                s = fmaf(Wl[c * 17 + i], mode ? Rl[i * 16 + j] : Rl[j * 16 + i], s);
            a.WT[v][(size_t)(h * 16 + j) * D + c] = f2bf(s);
        }
        if (tid < 16) {
            const float* b = a.b[v];
            float s = 0.f;
            #pragma unroll
            for (int i = 0; i < 16; ++i)
                s = fmaf(b[h * 16 + i], mode ? Rl[i * 16 + tid] : Rl[tid * 16 + i], s);
            a.bf[v][h * 16 + tid] = s;
        }
    } else {
        int base = (bid - 112) * 1024 + tid * 4;
        if (base + 4 <= S) {
            *(int4*)&cnt[base] = make_int4(0, 0, 0, 0);
        } else {
            for (int i = base; i < S; ++i) cnt[i] = 0;
        }
    }
}

// ---------- fused MFMA multi-output projection, both node types in one launch ----------
#define ASTRIDE 136
struct ProjFusedArgs {
    const float* X[2];
    int N[2], nmat[2], nblk0;
    const unsigned short* wt[2][5];
    const float* bias[2][5];
    unsigned short* out[2][5];
};

__global__ __launch_bounds__(256) void proj_fused_kernel(ProjFusedArgs a)
{
    __shared__ unsigned short As[64 * ASTRIDE];
    __shared__ unsigned short Cs[64 * ASTRIDE];
    const int tid = threadIdx.x;
    const int w = tid >> 6;
    const int l = tid & 63;
    const int seg = (blockIdx.x >= a.nblk0) ? 1 : 0;
    const int row0 = (blockIdx.x - (seg ? a.nblk0 : 0)) * 64;
    const float* X = a.X[seg];
    const int N = a.N[seg];
    const int nm = a.nmat[seg];

    #pragma unroll
    for (int p = 0; p < 8; ++p) {
        int f = p * 256 + tid;
        int r = f >> 5;
        int c4 = f & 31;
        int row = row0 + r; if (row >= N) row = N - 1;
        float4 xv = *(const float4*)&X[(size_t)row * D + c4 * 4];
        unsigned int lo = pack2(f2bf(xv.x), f2bf(xv.y));
        unsigned int hi = pack2(f2bf(xv.z), f2bf(xv.w));
        *(uint2*)&As[r * ASTRIDE + c4 * 4] = make_uint2(lo, hi);
    }
    __syncthreads();

    const int lrow = l & 15;
    const int lk8 = (l >> 4) * 8;

    for (int m = 0; m < nm; ++m) {
        const unsigned short* WT = a.wt[seg][m];
        bf16x8 bfrag[2][4];
        #pragma unroll
        for (int cf = 0; cf < 2; ++cf)
            #pragma unroll
            for (int kc = 0; kc < 4; ++kc)
                bfrag[cf][kc] = *(const bf16x8*)&WT[(size_t)(w * 32 + cf * 16 + lrow) * D + kc * 32 + lk8];

        f32x4 acc[4][2];
        #pragma unroll
        for (int rf = 0; rf < 4; ++rf) {
            acc[rf][0] = (f32x4){0.f, 0.f, 0.f, 0.f};
            acc[rf][1] = (f32x4){0.f, 0.f, 0.f, 0.f};
        }
        #pragma unroll
        for (int rf = 0; rf < 4; ++rf) {
            bf16x8 afrag[4];
            #pragma unroll
            for (int kc = 0; kc < 4; ++kc)
                afrag[kc] = *(const bf16x8*)&As[(rf * 16 + lrow) * ASTRIDE + kc * 32 + lk8];
            #pragma unroll
            for (int kc = 0; kc < 4; ++kc) {
                acc[rf][0] = __builtin_amdgcn_mfma_f32_16x16x32_bf16(afrag[kc], bfrag[0][kc], acc[rf][0], 0, 0, 0);
                acc[rf][1] = __builtin_amdgcn_mfma_f32_16x16x32_bf16(afrag[kc], bfrag[1][kc], acc[rf][1], 0, 0, 0);
            }
        }
        float bias0 = a.bias[seg][m][w * 32 + lrow];
        float bias1 = a.bias[seg][m][w * 32 + 16 + lrow];
        #pragma unroll
        for (int rf = 0; rf < 4; ++rf) {
            #pragma unroll
            for (int r = 0; r < 4; ++r) {
                int lr = rf * 16 + (l >> 4) * 4 + r;
                Cs[lr * ASTRIDE + w * 32 + lrow]      = f2bf(acc[rf][0][r] + bias0);
                Cs[lr * ASTRIDE + w * 32 + 16 + lrow] = f2bf(acc[rf][1][r] + bias1);
            }
        }
        __syncthreads();
        unsigned short* O = a.out[seg][m];
        #pragma unroll
        for (int p = 0; p < 4; ++p) {
            int idx = p * 256 + tid;
            int r = idx >> 4, c8 = idx & 15;
            int row = row0 + r;
            if (row < N)
                *(uint4*)&O[(size_t)row * D + c8 * 8] = *(const uint4*)&Cs[r * ASTRIDE + c8 * 8];
        }
        __syncthreads();
    }
}

// ---------- fused MFMA out-GEMM (both node types) ----------
struct OutFusedArgs {
    const unsigned short* T1[2]; const unsigned short* T2[2];
    const unsigned short* WT[2]; const float* bias[2];
    const float* skip[2]; const float* X[2]; float* O[2];
    int N[2], nsrc[2], nblk0;
};

__global__ __launch_bounds__(256) void out_fused_kernel(OutFusedArgs a)
{
    __shared__ unsigned short As[64 * ASTRIDE];
    const int tid = threadIdx.x;
    const int w = tid >> 6;
    const int l = tid & 63;
    const int seg = (blockIdx.x >= a.nblk0) ? 1 : 0;
    const int row0 = (blockIdx.x - (seg ? a.nblk0 : 0)) * 64;
    const int N = a.N[seg];
    const int nsrc = a.nsrc[seg];
    const unsigned short* T1 = a.T1[seg];
    const unsigned short* T2 = a.T2[seg];

    #pragma unroll
    for (int p = 0; p < 4; ++p) {
        int idx = p * 256 + tid;
        int r = idx >> 4;
        int c8 = idx & 15;
        int row = row0 + r; if (row >= N) row = N - 1;
        uint4 tv = *(const uint4*)&T1[(size_t)row * D + c8 * 8];
        float v[8]; unpack8(tv, v);
        #pragma unroll
        for (int i = 0; i < 8; ++i) v[i] = fmaxf(v[i], 0.f);
        if (nsrc == 2) {
            uint4 uv = *(const uint4*)&T2[(size_t)row * D + c8 * 8];
            float u[8]; unpack8(uv, u);
            #pragma unroll
            for (int i = 0; i < 8; ++i) v[i] = 0.5f * (v[i] + fmaxf(u[i], 0.f));
        }
        uint4 pk;
        pk.x = pack2(f2bf(v[0]), f2bf(v[1]));
        pk.y = pack2(f2bf(v[2]), f2bf(v[3]));
        pk.z = pack2(f2bf(v[4]), f2bf(v[5]));
        pk.w = pack2(f2bf(v[6]), f2bf(v[7]));
        *(uint4*)&As[r * ASTRIDE + c8 * 8] = pk;
    }
    __syncthreads();

    const int lrow = l & 15;
    const int lk8 = (l >> 4) * 8;
    const unsigned short* WT = a.WT[seg];

    bf16x8 bfrag[2][4];
    #pragma unroll
    for (int cf = 0; cf < 2; ++cf)
        #pragma unroll
        for (int kc = 0; kc < 4; ++kc)
            bfrag[cf][kc] = *(const bf16x8*)&WT[(size_t)(w * 32 + cf * 16 + lrow) * D + kc * 32 + lk8];

    f32x4 acc[4][2];
    #pragma unroll
    for (int rf = 0; rf < 4; ++rf) {
        acc[rf][0] = (f32x4){0.f, 0.f, 0.f, 0.f};
        acc[rf][1] = (f32x4){0.f, 0.f, 0.f, 0.f};
    }
    #pragma unroll
    for (int rf = 0; rf < 4; ++rf) {
        bf16x8 afrag[4];
        #pragma unroll
        for (int kc = 0; kc < 4; ++kc)
            afrag[kc] = *(const bf16x8*)&As[(rf * 16 + lrow) * ASTRIDE + kc * 32 + lk8];
        #pragma unroll
        for (int kc = 0; kc < 4; ++kc) {
            acc[rf][0] = __builtin_amdgcn_mfma_f32_16x16x32_bf16(afrag[kc], bfrag[0][kc], acc[rf][0], 0, 0, 0);
            acc[rf][1] = __builtin_amdgcn_mfma_f32_16x16x32_bf16(afrag[kc], bfrag[1][kc], acc[rf][1], 0, 0, 0);
        }
    }
    float alpha = 1.f / (1.f + __expf(-a.skip[seg][0]));
    float om = 1.f - alpha;
    float bias0 = a.bias[seg][w * 32 + lrow];
    float bias1 = a.bias[seg][w * 32 + 16 + lrow];
    const float* X = a.X[seg];
    float* O = a.O[seg];
    #pragma unroll
    for (int rf = 0; rf < 4; ++rf) {
        #pragma unroll
        for (int r = 0; r < 4; ++r) {
            int row = row0 + rf * 16 + (l >> 4) * 4 + r;
            if (row < N) {
                int c0 = w * 32 + lrow;
                float x0 = X[(size_t)row * D + c0];
                float x1 = X[(size_t)row * D + c0 + 16];
                O[(size_t)row * D + c0]      = (acc[rf][0][r] + bias0) * alpha + x0 * om;
                O[(size_t)row * D + c0 + 16] = (acc[rf][1][r] + bias1) * alpha + x1 * om;
            }
        }
    }
}

// ---------- combined CSR build over 3 etypes in slot space ----------
struct EdgeArgs {
    const int* src[3]; const int* dst[3]; int base[3]; int E;
};

// hist, 4 edges/thread; records each edge's rank within its dst segment
__global__ __launch_bounds__(256) void hist_all_kernel(EdgeArgs a, int* __restrict__ cnt,
                                                       int* __restrict__ rank) {
    int E = a.E;
    int perE = (E + 3) >> 2;                 // vec4 threads per etype
    int gid = blockIdx.x * 256 + threadIdx.x;
    int t = gid / perE;
    if (t >= 3) return;
    int e4 = (gid - t * perE) * 4;
    const int* dstp = a.dst[t];
    int b = a.base[t];
    if (e4 + 4 <= E) {
        int4 d = *(const int4*)&dstp[e4];
        int4 r;
        r.x = atomicAdd(&cnt[b + d.x], 1);
        r.y = atomicAdd(&cnt[b + d.y], 1);
        r.z = atomicAdd(&cnt[b + d.z], 1);
        r.w = atomicAdd(&cnt[b + d.w], 1);
        *(int4*)&rank[t * E + e4] = r;
    } else {
        for (int e = e4; e < E; ++e)
            rank[t * E + e] = atomicAdd(&cnt[b + dstp[e]], 1);
    }
}

// scan1: per-tile partial sums
__global__ __launch_bounds__(SCAN_BLK) void scan1_kernel(
    const int* __restrict__ cnt, int* __restrict__ bsum, int n)
{
    __shared__ int sh[SCAN_BLK];
    int tid = threadIdx.x;
    int base = blockIdx.x * SCAN_TILE + tid * SCAN_ITEMS;
    int s = 0;
    #pragma unroll
    for (int i = 0; i < SCAN_ITEMS; ++i) {
        int idx = base + i;
        if (idx < n) s += cnt[idx];
    }
    sh[tid] = s; __syncthreads();
    for (int o = SCAN_BLK / 2; o > 0; o >>= 1) {
        if (tid < o) sh[tid] += sh[tid + o];
        __syncthreads();
    }
    if (tid == 0) bsum[blockIdx.x] = sh[0];
}

// scan3 with integrated block-prefix over bsum (offs only)
__global__ __launch_bounds__(SCAN_BLK) void scan3_kernel(
    const int* __restrict__ cnt, const int* __restrict__ bsum,
    int* __restrict__ offs, int n)
{
    __shared__ int red[SCAN_BLK];
    __shared__ int sh[SCAN_BLK];
    const int tid = threadIdx.x;
    int pre = 0;
    for (int i = tid; i < blockIdx.x; i += SCAN_BLK) pre += bsum[i];
    red[tid] = pre; __syncthreads();
    for (int o = SCAN_BLK / 2; o > 0; o >>= 1) {
        if (tid < o) red[tid] += red[tid + o];
        __syncthreads();
    }
    int base0 = red[0];

    int base = blockIdx.x * SCAN_TILE + tid * SCAN_ITEMS;
    int v[SCAN_ITEMS];
    int s = 0;
    #pragma unroll
    for (int i = 0; i < SCAN_ITEMS; ++i) {
        int idx = base + i;
        v[i] = (idx < n) ? cnt[idx] : 0;
        s += v[i];
    }
    sh[tid] = s; __syncthreads();
    for (int o = 1; o < SCAN_BLK; o <<= 1) {
        int t = (tid >= o) ? sh[tid - o] : 0;
        __syncthreads();
        sh[tid] += t;
        __syncthreads();
    }
    int off = base0 + sh[tid] - s;
    #pragma unroll
    for (int i = 0; i < SCAN_ITEMS; ++i) {
        int idx = base + i;
        if (idx < n) {
            offs[idx] = off;
            off += v[i];
            if (idx == n - 1) offs[n] = off;
        }
    }
}

// atomic-free scatter, 4 edges/thread: position = offs[dst] + rank
__global__ __launch_bounds__(256) void scatter_all_kernel(
    EdgeArgs a, const int* __restrict__ offs, const int* __restrict__ rank,
    int* __restrict__ csr_src)
{
    int E = a.E;
    int perE = (E + 3) >> 2;
    int gid = blockIdx.x * 256 + threadIdx.x;
    int t = gid / perE;
    if (t >= 3) return;
    int e4 = (gid - t * perE) * 4;
    const int* dstp = a.dst[t];
    const int* srcp = a.src[t];
    int b = a.base[t];
    if (e4 + 4 <= E) {
        int4 d = *(const int4*)&dstp[e4];
        int4 r = *(const int4*)&rank[t * E + e4];
        int4 s = *(const int4*)&srcp[e4];
        csr_src[offs[b + d.x] + r.x] = s.x;
        csr_src[offs[b + d.y] + r.y] = s.y;
        csr_src[offs[b + d.z] + r.z] = s.z;
        csr_src[offs[b + d.w] + r.w] = s.w;
    } else {
        for (int e = e4; e < E; ++e)
            csr_src[offs[b + dstp[e]] + rank[t * E + e]] = srcp[e];
    }
}

// ---------- fused per-dst softmax + aggregate, 2 lanes per (slot,head), 2-edge unroll ----------
struct AggArgs {
    const unsigned short* K[3];
    const unsigned short* Q[3];
    const unsigned short* V[3];
    const float* pri[3];
    unsigned short* T[3];
};

__global__ __launch_bounds__(256) void csr_agg_all_kernel(
    const int* __restrict__ offs, const int* __restrict__ csr_src,
    AggArgs a, int n_b, int n_a)
{
    int gid = blockIdx.x * 256 + threadIdx.x;
    int si = gid >> 4;
    int hp = gid & 15;
    int h = hp >> 1, p = hp & 1;
    int S = 2 * n_b + n_a;
    if (si >= S) return;
    int s = si;
    int t = (s < n_b) ? 0 : ((s < 2 * n_b) ? 1 : 2);
    int n = s - ((t == 2) ? 2 * n_b : t * n_b);

    const unsigned short *Kp, *Qp, *Vp; const float* prip; unsigned short* Tp;
    if (t == 0)      { Kp=a.K[0]; Qp=a.Q[0]; Vp=a.V[0]; prip=a.pri[0]; Tp=a.T[0]; }
    else if (t == 1) { Kp=a.K[1]; Qp=a.Q[1]; Vp=a.V[1]; prip=a.pri[1]; Tp=a.T[1]; }
    else             { Kp=a.K[2]; Qp=a.Q[2]; Vp=a.V[2]; prip=a.pri[2]; Tp=a.T[2]; }

    int e0 = offs[s], e1 = offs[s + 1];
    const int sub = h * DK + p * 8;

    uint4 q = *(const uint4*)(Qp + (size_t)n * D + sub);
    float qv[8]; unpack8(q, qv);
    float ps = prip[h] * 0.25f;

    float acc[8];
    #pragma unroll
    for (int i = 0; i < 8; ++i) acc[i] = 0.f;
    float den = 0.f;

    int e = e0;
    for (; e + 2 <= e1; e += 2) {
        int s0 = csr_src[e], s1 = csr_src[e + 1];
        uint4 k0 = *(const uint4*)(Kp + (size_t)s0 * D + sub);
        uint4 v0 = *(const uint4*)(Vp + (size_t)s0 * D + sub);
        uint4 k1 = *(const uint4*)(Kp + (size_t)s1 * D + sub);
        uint4 v1 = *(const uint4*)(Vp + (size_t)s1 * D + sub);
        float ka[8], kb[8];
        unpack8(k0, ka); unpack8(k1, kb);
        float d0 = 0.f, d1 = 0.f;
        #pragma unroll
        for (int i = 0; i < 8; ++i) {
            d0 = fmaf(ka[i], qv[i], d0);
            d1 = fmaf(kb[i], qv[i], d1);
        }
        d0 += __shfl_xor(d0, 1, 64);
        d1 += __shfl_xor(d1, 1, 64);
        float ea0 = __expf(d0 * ps);
        float ea1 = __expf(d1 * ps);
        den += ea0 + ea1;
        float va[8], vb[8];
        unpack8(v0, va); unpack8(v1, vb);
        #pragma unroll
        for (int i = 0; i < 8; ++i)
            acc[i] = fmaf(ea0, va[i], fmaf(ea1, vb[i], acc[i]));
    }
    if (e < e1) {
        int s0 = csr_src[e];
        uint4 k = *(const uint4*)(Kp + (size_t)s0 * D + sub);
        uint4 v = *(const uint4*)(Vp + (size_t)s0 * D + sub);
        float kv[8]; unpack8(k, kv);
        float d = 0.f;
        #pragma unroll
        for (int i = 0; i < 8; ++i) d = fmaf(kv[i], qv[i], d);
        d += __shfl_xor(d, 1, 64);
        float ea = __expf(d * ps);
        den += ea;
        float vv[8]; unpack8(v, vv);
        #pragma unroll
        for (int i = 0; i < 8; ++i) acc[i] = fmaf(ea, vv[i], acc[i]);
    }
    float inv = 1.f / fmaxf(den, 1e-9f);
    unsigned short ob[8];
    #pragma unroll
    for (int i = 0; i < 8; ++i) ob[i] = f2bf(acc[i] * inv);
    uint4 o0;
    o0.x = pack2(ob[0], ob[1]);  o0.y = pack2(ob[2], ob[3]);
    o0.z = pack2(ob[4], ob[5]);  o0.w = pack2(ob[6], ob[7]);
    *(uint4*)(Tp + (size_t)n * D + sub) = o0;
}

extern "C" void kernel_launch(void* const* d_in, const int* in_sizes, int n_in,
                              void* d_out, int out_size, void* d_ws, size_t ws_size,
                              hipStream_t stream) {
    const float* x_a = (const float*)d_in[0];
    const float* x_b = (const float*)d_in[1];
    const int* src_ab = (const int*)d_in[2];
    const int* dst_ab = (const int*)d_in[3];
    const int* src_ba = (const int*)d_in[4];
    const int* dst_ba = (const int*)d_in[5];
    const int* src_bb = (const int*)d_in[6];
    const int* dst_bb = (const int*)d_in[7];
    const float* Wk_a = (const float*)d_in[8];  const float* bk_a = (const float*)d_in[9];
    const float* Wq_a = (const float*)d_in[10]; const float* bq_a = (const float*)d_in[11];
    const float* Wv_a = (const float*)d_in[12]; const float* bv_a = (const float*)d_in[13];
    const float* Wa_a = (const float*)d_in[14]; const float* ba_a = (const float*)d_in[15];
    const float* skip_a = (const float*)d_in[16];
    const float* Wk_b = (const float*)d_in[17]; const float* bk_b = (const float*)d_in[18];
    const float* Wq_b = (const float*)d_in[19]; const float* bq_b = (const float*)d_in[20];
    const float* Wv_b = (const float*)d_in[21]; const float* bv_b = (const float*)d_in[22];
    const float* Wa_b = (const float*)d_in[23]; const float* ba_b = (const float*)d_in[24];
    const float* skip_b = (const float*)d_in[25];
    const float* pri_ab = (const float*)d_in[26];
    const float* att_ab = (const float*)d_in[27];
    const float* msg_ab = (const float*)d_in[28];
    const float* pri_ba = (const float*)d_in[29];
    const float* att_ba = (const float*)d_in[30];
    const float* msg_ba = (const float*)d_in[31];
    const float* pri_bb = (const float*)d_in[32];
    const float* att_bb = (const float*)d_in[33];
    const float* msg_bb = (const float*)d_in[34];

    const int n_a = in_sizes[0] / D;
    const int n_b = in_sizes[1] / D;
    const int E = in_sizes[2];
    const int S = 2 * n_b + n_a;

    size_t off = 0;
    char* base = (char*)d_ws;
    auto alloc = [&](size_t bytes) -> void* {
        void* r = base + off;
        off += (bytes + 255) & ~(size_t)255;
        return r;
    };
    unsigned short* k_a = (unsigned short*)alloc((size_t)n_a * D * 2);
    unsigned short* k_b = (unsigned short*)alloc((size_t)n_b * D * 2);
    unsigned short* qab = (unsigned short*)alloc((size_t)n_b * D * 2);
    unsigned short* qbb = (unsigned short*)alloc((size_t)n_b * D * 2);
    unsigned short* qba = (unsigned short*)alloc((size_t)n_a * D * 2);
    unsigned short* vab = (unsigned short*)alloc((size_t)n_a * D * 2);
    unsigned short* vbb = (unsigned short*)alloc((size_t)n_b * D * 2);
    unsigned short* vba = (unsigned short*)alloc((size_t)n_b * D * 2);
    unsigned short* t_a  = (unsigned short*)alloc((size_t)n_a * D * 2);
    unsigned short* t_b1 = (unsigned short*)alloc((size_t)n_b * D * 2);
    unsigned short* t_b2 = (unsigned short*)alloc((size_t)n_b * D * 2);
    int* cnt    = (int*)alloc((size_t)S * 4);
    int* offs   = (int*)alloc(((size_t)S + 1) * 4);
    int* rank   = (int*)alloc((size_t)3 * E * 4);
    int* csr_src= (int*)alloc((size_t)3 * E * 4);
    int* bsum   = (int*)alloc(256 * 4);
    unsigned short* wt_plain[4];
    for (int i = 0; i < 4; ++i) wt_plain[i] = (unsigned short*)alloc((size_t)D * D * 2);
    unsigned short* wt_fold[6];
    float* bf_fold[6];
    for (int i = 0; i < 6; ++i) {
        wt_fold[i] = (unsigned short*)alloc((size_t)D * D * 2);
        bf_fold[i] = (float*)alloc((size_t)D * 4);
    }

    // prep: transposes (Wk_a, Wk_b, Wa_a, Wa_b), folds, zero cnt
    WTIn win; WTOut wout;
    const float* worig[4] = {Wk_a, Wk_b, Wa_a, Wa_b};
    for (int i = 0; i < 4; ++i) { win.w[i] = worig[i]; wout.wt[i] = wt_plain[i]; }
    FoldArgs fa;
    const float* fW[6] = {Wq_b, Wq_b, Wq_a, Wv_a, Wv_b, Wv_b};
    const float* fR[6] = {att_ab, att_bb, att_ba, msg_ab, msg_bb, msg_ba};
    const float* fb[6] = {bq_b, bq_b, bq_a, bv_a, bv_b, bv_b};
    int fm[6] = {0, 0, 0, 1, 1, 1};
    for (int i = 0; i < 6; ++i) {
        fa.W[i] = fW[i]; fa.R[i] = fR[i]; fa.b[i] = fb[i];
        fa.WT[i] = wt_fold[i]; fa.bf[i] = bf_fold[i]; fa.mode[i] = fm[i];
    }
    int nz = (S + 1023) / 1024;
    prep_kernel<<<112 + nz, 256, 0, stream>>>(win, wout, fa, cnt, S);

    // combined CSR build (rank-in-hist vec4, two-kernel scan, atomic-free scatter vec4)
    EdgeArgs ea;
    ea.src[0] = src_ab; ea.dst[0] = dst_ab;
    ea.src[1] = src_bb; ea.dst[1] = dst_bb;
    ea.src[2] = src_ba; ea.dst[2] = dst_ba;
    ea.base[0] = 0; ea.base[1] = n_b; ea.base[2] = 2 * n_b;
    ea.E = E;
    int perE = (E + 3) >> 2;
    int gv = (3 * perE + 255) / 256;
    hist_all_kernel<<<gv, 256, 0, stream>>>(ea, cnt, rank);
    int nb = (S + SCAN_TILE - 1) / SCAN_TILE;
    scan1_kernel<<<nb, SCAN_BLK, 0, stream>>>(cnt, bsum, S);
    scan3_kernel<<<nb, SCAN_BLK, 0, stream>>>(cnt, bsum, offs, S);
    scatter_all_kernel<<<gv, 256, 0, stream>>>(ea, offs, rank, csr_src);

    // fused projections (both node types)
    const int gb_a = (n_a + 63) / 64;
    const int gb_b = (n_b + 63) / 64;
    ProjFusedArgs pa;
    pa.X[0] = x_a; pa.N[0] = n_a; pa.nmat[0] = 3;
    pa.X[1] = x_b; pa.N[1] = n_b; pa.nmat[1] = 5;
    pa.nblk0 = gb_a;
    pa.wt[0][0] = wt_plain[0]; pa.bias[0][0] = bk_a;       pa.out[0][0] = k_a;
    pa.wt[0][1] = wt_fold[2];  pa.bias[0][1] = bf_fold[2]; pa.out[0][1] = qba;
    pa.wt[0][2] = wt_fold[3];  pa.bias[0][2] = bf_fold[3]; pa.out[0][2] = vab;
    pa.wt[0][3] = wt_plain[0]; pa.bias[0][3] = bk_a;       pa.out[0][3] = k_a;   // unused
    pa.wt[0][4] = wt_plain[0]; pa.bias[0][4] = bk_a;       pa.out[0][4] = k_a;   // unused
    pa.wt[1][0] = wt_plain[1]; pa.bias[1][0] = bk_b;       pa.out[1][0] = k_b;
    pa.wt[1][1] = wt_fold[0];  pa.bias[1][1] = bf_fold[0]; pa.out[1][1] = qab;
    pa.wt[1][2] = wt_fold[1];  pa.bias[1][2] = bf_fold[1]; pa.out[1][2] = qbb;
    pa.wt[1][3] = wt_fold[4];  pa.bias[1][3] = bf_fold[4]; pa.out[1][3] = vbb;
    pa.wt[1][4] = wt_fold[5];  pa.bias[1][4] = bf_fold[5]; pa.out[1][4] = vba;
    proj_fused_kernel<<<gb_a + gb_b, 256, 0, stream>>>(pa);

    // fused aggregate (all etypes, natural slot order, 2 lanes/head, 2-edge unroll)
    AggArgs aa;
    aa.K[0] = k_a; aa.Q[0] = qab; aa.V[0] = vab; aa.pri[0] = pri_ab; aa.T[0] = t_b1;
    aa.K[1] = k_b; aa.Q[1] = qbb; aa.V[1] = vbb; aa.pri[1] = pri_bb; aa.T[1] = t_b2;
    aa.K[2] = k_b; aa.Q[2] = qba; aa.V[2] = vba; aa.pri[2] = pri_ba; aa.T[2] = t_a;
    int gs = (S * 16 + 255) / 256;
    csr_agg_all_kernel<<<gs, 256, 0, stream>>>(offs, csr_src, aa, n_b, n_a);

    // fused final skip-connection GEMMs
    float* out_a = (float*)d_out;
    float* out_b = (float*)d_out + (size_t)n_a * D;
    OutFusedArgs oa;
    oa.T1[0] = t_a;  oa.T2[0] = t_a;  oa.WT[0] = wt_plain[2]; oa.bias[0] = ba_a;
    oa.skip[0] = skip_a; oa.X[0] = x_a; oa.O[0] = out_a; oa.N[0] = n_a; oa.nsrc[0] = 1;
    oa.T1[1] = t_b1; oa.T2[1] = t_b2; oa.WT[1] = wt_plain[3]; oa.bias[1] = ba_b;
    oa.skip[1] = skip_b; oa.X[1] = x_b; oa.O[1] = out_b; oa.N[1] = n_b; oa.nsrc[1] = 2;
    oa.nblk0 = gb_a;
    out_fused_kernel<<<gb_a + gb_b, 256, 0, stream>>>(oa);
}

// Round 15
// 349.375 us; speedup vs baseline: 1.4074x; 1.0017x over previous
//
#include <hip/hip_runtime.h>
#include <hip/hip_bf16.h>
#include <stdint.h>

#define D 128
#define H 8
#define DK 16

#define SCAN_BLK 256
#define SCAN_ITEMS 8
#define SCAN_TILE (SCAN_BLK * SCAN_ITEMS)

typedef __attribute__((ext_vector_type(8))) short bf16x8;
typedef __attribute__((ext_vector_type(4))) float f32x4;

// ---------- bf16 helpers ----------
__device__ __forceinline__ unsigned short f2bf(float f) {
    unsigned int u = __float_as_uint(f);
    u = u + 0x7fffu + ((u >> 16) & 1u);      // round-to-nearest-even
    return (unsigned short)(u >> 16);
}
__device__ __forceinline__ float bfl(unsigned int u) { return __uint_as_float(u << 16); }
__device__ __forceinline__ float bfh(unsigned int u) { return __uint_as_float(u & 0xffff0000u); }
__device__ __forceinline__ unsigned int pack2(unsigned short a, unsigned short b) {
    return (unsigned int)a | ((unsigned int)b << 16);
}
__device__ __forceinline__ void unpack8(uint4 u, float* o) {
    o[0]=bfl(u.x); o[1]=bfh(u.x); o[2]=bfl(u.y); o[3]=bfh(u.y);
    o[4]=bfl(u.z); o[5]=bfh(u.z); o[6]=bfl(u.w); o[7]=bfh(u.w);
}

// ---------- combined prep: W^T transposes + relation folds + cnt zeroing ----------
struct WTIn  { const float* w[4]; };
struct WTOut { unsigned short* wt[4]; };
struct FoldArgs {
    const float* W[6]; const float* R[6]; const float* b[6];
    unsigned short* WT[6]; float* bf[6]; int mode[6];
};

__global__ __launch_bounds__(256) void prep_kernel(WTIn in, WTOut out, FoldArgs a,
                                                   int* __restrict__ cnt, int S) {
    __shared__ float tile[32][33];
    __shared__ float Wl[128 * 17];
    __shared__ float Rl[256];
    int bid = blockIdx.x;
    int tid = threadIdx.x;
    if (bid < 64) {
        int mat = bid >> 4;
        int t = bid & 15;
        int k0 = (t >> 2) * 32, c0 = (t & 3) * 32;
        const float* W = in.w[mat];
        unsigned short* WT = out.wt[mat];
        int lr = tid >> 5, lc = tid & 31;
        #pragma unroll
        for (int p = 0; p < 4; ++p)
            tile[p * 8 + lr][lc] = W[(size_t)(k0 + p * 8 + lr) * D + c0 + lc];
        __syncthreads();
        #pragma unroll
        for (int p = 0; p < 4; ++p)
            WT[(size_t)(c0 + p * 8 + lr) * D + k0 + lc] = f2bf(tile[lc][p * 8 + lr]);
    } else if (bid < 112) {
        int v = (bid - 64) >> 3, h = (bid - 64) & 7;
        const float* W = a.W[v];
        #pragma unroll
        for (int p = 0; p < 8; ++p) {
            int idx = p * 256 + tid;
            int c = idx >> 4, i = idx & 15;
            Wl[c * 17 + i] = W[(size_t)c * D + h * 16 + i];
        }
        Rl[tid] = a.R[v][h * 256 + tid];
        __syncthreads();
        int mode = a.mode[v];
        int c = tid & 127, jb = (tid >> 7) * 8;
        #pragma unroll
        for (int jj = 0; jj < 8; ++jj) {
            int j = jb + jj;
            float s = 0.f;
            #pragma unroll
            for (int i = 0; i < 16; ++i)
                s = fmaf(Wl[c * 17 + i], mode ? Rl[i * 16 + j] : Rl[j * 16 + i], s);
            a.WT[v][(size_t)(h * 16 + j) * D + c] = f2bf(s);
        }
        if (tid < 16) {
            const float* b = a.b[v];
            float s = 0.f;
            #pragma unroll
            for (int i = 0; i < 16; ++i)
                s = fmaf(b[h * 16 + i], mode ? Rl[i * 16 + tid] : Rl[tid * 16 + i], s);
            a.bf[v][h * 16 + tid] = s;
        }
    } else {
        int base = (bid - 112) * 1024 + tid * 4;
        if (base + 4 <= S) {
            *(int4*)&cnt[base] = make_int4(0, 0, 0, 0);
        } else {
            for (int i = base; i < S; ++i) cnt[i] = 0;
        }
    }
}

// ---------- fused MFMA multi-output projection, both node types in one launch ----------
// Cs is half-height (32 rows) + XOR-swizzled columns: 26.1KB LDS -> 6 blocks/CU,
// and the repack stores are bank-conflict-free.
#define ASTRIDE 136
struct ProjFusedArgs {
    const float* X[2];
    int N[2], nmat[2], nblk0;
    const unsigned short* wt[2][5];
    const float* bias[2][5];
    unsigned short* out[2][5];
};

__global__ __launch_bounds__(256) void proj_fused_kernel(ProjFusedArgs a)
{
    __shared__ unsigned short As[64 * ASTRIDE];
    __shared__ unsigned short Cs[32 * ASTRIDE];
    const int tid = threadIdx.x;
    const int w = tid >> 6;
    const int l = tid & 63;
    const int seg = (blockIdx.x >= a.nblk0) ? 1 : 0;
    const int row0 = (blockIdx.x - (seg ? a.nblk0 : 0)) * 64;
    const float* X = a.X[seg];
    const int N = a.N[seg];
    const int nm = a.nmat[seg];

    #pragma unroll
    for (int p = 0; p < 8; ++p) {
        int f = p * 256 + tid;
        int r = f >> 5;
        int c4 = f & 31;
        int row = row0 + r; if (row >= N) row = N - 1;
        float4 xv = *(const float4*)&X[(size_t)row * D + c4 * 4];
        unsigned int lo = pack2(f2bf(xv.x), f2bf(xv.y));
        unsigned int hi = pack2(f2bf(xv.z), f2bf(xv.w));
        *(uint2*)&As[r * ASTRIDE + c4 * 4] = make_uint2(lo, hi);
    }
    __syncthreads();

    const int lrow = l & 15;
    const int q = l >> 4;
    const int lk8 = q * 8;

    for (int m = 0; m < nm; ++m) {
        const unsigned short* WT = a.wt[seg][m];
        bf16x8 bfrag[2][4];
        #pragma unroll
        for (int cf = 0; cf < 2; ++cf)
            #pragma unroll
            for (int kc = 0; kc < 4; ++kc)
                bfrag[cf][kc] = *(const bf16x8*)&WT[(size_t)(w * 32 + cf * 16 + lrow) * D + kc * 32 + lk8];

        f32x4 acc[4][2];
        #pragma unroll
        for (int rf = 0; rf < 4; ++rf) {
            acc[rf][0] = (f32x4){0.f, 0.f, 0.f, 0.f};
            acc[rf][1] = (f32x4){0.f, 0.f, 0.f, 0.f};
        }
        #pragma unroll
        for (int rf = 0; rf < 4; ++rf) {
            bf16x8 afrag[4];
            #pragma unroll
            for (int kc = 0; kc < 4; ++kc)
                afrag[kc] = *(const bf16x8*)&As[(rf * 16 + lrow) * ASTRIDE + kc * 32 + lk8];
            #pragma unroll
            for (int kc = 0; kc < 4; ++kc) {
                acc[rf][0] = __builtin_amdgcn_mfma_f32_16x16x32_bf16(afrag[kc], bfrag[0][kc], acc[rf][0], 0, 0, 0);
                acc[rf][1] = __builtin_amdgcn_mfma_f32_16x16x32_bf16(afrag[kc], bfrag[1][kc], acc[rf][1], 0, 0, 0);
            }
        }
        float bias0 = a.bias[seg][m][w * 32 + lrow];
        float bias1 = a.bias[seg][m][w * 32 + 16 + lrow];
        unsigned short* O = a.out[seg][m];
        const int xk = q * 16;                  // column XOR key (16-short granularity)
        #pragma unroll
        for (int half = 0; half < 2; ++half) {
            #pragma unroll
            for (int rf2 = 0; rf2 < 2; ++rf2) {
                int rf = half * 2 + rf2;
                #pragma unroll
                for (int r = 0; r < 4; ++r) {
                    int lr2 = rf2 * 16 + q * 4 + r;   // 0..31
                    Cs[lr2 * ASTRIDE + ((w * 32 + lrow) ^ xk)]      = f2bf(acc[rf][0][r] + bias0);
                    Cs[lr2 * ASTRIDE + ((w * 32 + 16 + lrow) ^ xk)] = f2bf(acc[rf][1][r] + bias1);
                }
            }
            __syncthreads();
            #pragma unroll
            for (int p = 0; p < 2; ++p) {
                int idx = p * 256 + tid;
                int r2 = idx >> 4, c8 = idx & 15;
                int row = row0 + half * 32 + r2;
                int rk = ((r2 >> 2) & 3) * 16;
                if (row < N)
                    *(uint4*)&O[(size_t)row * D + c8 * 8] =
                        *(const uint4*)&Cs[r2 * ASTRIDE + (((c8 * 8) ^ rk))];
            }
            __syncthreads();
        }
    }
}

// ---------- fused MFMA out-GEMM (both node types) ----------
struct OutFusedArgs {
    const unsigned short* T1[2]; const unsigned short* T2[2];
    const unsigned short* WT[2]; const float* bias[2];
    const float* skip[2]; const float* X[2]; float* O[2];
    int N[2], nsrc[2], nblk0;
};

__global__ __launch_bounds__(256) void out_fused_kernel(OutFusedArgs a)
{
    __shared__ unsigned short As[64 * ASTRIDE];
    const int tid = threadIdx.x;
    const int w = tid >> 6;
    const int l = tid & 63;
    const int seg = (blockIdx.x >= a.nblk0) ? 1 : 0;
    const int row0 = (blockIdx.x - (seg ? a.nblk0 : 0)) * 64;
    const int N = a.N[seg];
    const int nsrc = a.nsrc[seg];
    const unsigned short* T1 = a.T1[seg];
    const unsigned short* T2 = a.T2[seg];

    #pragma unroll
    for (int p = 0; p < 4; ++p) {
        int idx = p * 256 + tid;
        int r = idx >> 4;
        int c8 = idx & 15;
        int row = row0 + r; if (row >= N) row = N - 1;
        uint4 tv = *(const uint4*)&T1[(size_t)row * D + c8 * 8];
        float v[8]; unpack8(tv, v);
        #pragma unroll
        for (int i = 0; i < 8; ++i) v[i] = fmaxf(v[i], 0.f);
        if (nsrc == 2) {
            uint4 uv = *(const uint4*)&T2[(size_t)row * D + c8 * 8];
            float u[8]; unpack8(uv, u);
            #pragma unroll
            for (int i = 0; i < 8; ++i) v[i] = 0.5f * (v[i] + fmaxf(u[i], 0.f));
        }
        uint4 pk;
        pk.x = pack2(f2bf(v[0]), f2bf(v[1]));
        pk.y = pack2(f2bf(v[2]), f2bf(v[3]));
        pk.z = pack2(f2bf(v[4]), f2bf(v[5]));
        pk.w = pack2(f2bf(v[6]), f2bf(v[7]));
        *(uint4*)&As[r * ASTRIDE + c8 * 8] = pk;
    }
    __syncthreads();

    const int lrow = l & 15;
    const int lk8 = (l >> 4) * 8;
    const unsigned short* WT = a.WT[seg];

    bf16x8 bfrag[2][4];
    #pragma unroll
    for (int cf = 0; cf < 2; ++cf)
        #pragma unroll
        for (int kc = 0; kc < 4; ++kc)
            bfrag[cf][kc] = *(const bf16x8*)&WT[(size_t)(w * 32 + cf * 16 + lrow) * D + kc * 32 + lk8];

    f32x4 acc[4][2];
    #pragma unroll
    for (int rf = 0; rf < 4; ++rf) {
        acc[rf][0] = (f32x4){0.f, 0.f, 0.f, 0.f};
        acc[rf][1] = (f32x4){0.f, 0.f, 0.f, 0.f};
    }
    #pragma unroll
    for (int rf = 0; rf < 4; ++rf) {
        bf16x8 afrag[4];
        #pragma unroll
        for (int kc = 0; kc < 4; ++kc)
            afrag[kc] = *(const bf16x8*)&As[(rf * 16 + lrow) * ASTRIDE + kc * 32 + lk8];
        #pragma unroll
        for (int kc = 0; kc < 4; ++kc) {
            acc[rf][0] = __builtin_amdgcn_mfma_f32_16x16x32_bf16(afrag[kc], bfrag[0][kc], acc[rf][0], 0, 0, 0);
            acc[rf][1] = __builtin_amdgcn_mfma_f32_16x16x32_bf16(afrag[kc], bfrag[1][kc], acc[rf][1], 0, 0, 0);
        }
    }
    float alpha = 1.f / (1.f + __expf(-a.skip[seg][0]));
    float om = 1.f - alpha;
    float bias0 = a.bias[seg][w * 32 + lrow];
    float bias1 = a.bias[seg][w * 32 + 16 + lrow];
    const float* X = a.X[seg];
    float* O = a.O[seg];
    #pragma unroll
    for (int rf = 0; rf < 4; ++rf) {
        #pragma unroll
        for (int r = 0; r < 4; ++r) {
            int row = row0 + rf * 16 + (l >> 4) * 4 + r;
            if (row < N) {
                int c0 = w * 32 + lrow;
                float x0 = X[(size_t)row * D + c0];
                float x1 = X[(size_t)row * D + c0 + 16];
                O[(size_t)row * D + c0]      = (acc[rf][0][r] + bias0) * alpha + x0 * om;
                O[(size_t)row * D + c0 + 16] = (acc[rf][1][r] + bias1) * alpha + x1 * om;
            }
        }
    }
}

// ---------- combined CSR build over 3 etypes in slot space ----------
struct EdgeArgs {
    const int* src[3]; const int* dst[3]; int base[3]; int E;
};

// hist, 4 edges/thread; records each edge's rank within its dst segment
__global__ __launch_bounds__(256) void hist_all_kernel(EdgeArgs a, int* __restrict__ cnt,
                                                       int* __restrict__ rank) {
    int E = a.E;
    int perE = (E + 3) >> 2;                 // vec4 threads per etype
    int gid = blockIdx.x * 256 + threadIdx.x;
    int t = gid / perE;
    if (t >= 3) return;
    int e4 = (gid - t * perE) * 4;
    const int* dstp = a.dst[t];
    int b = a.base[t];
    if (e4 + 4 <= E) {
        int4 d = *(const int4*)&dstp[e4];
        int4 r;
        r.x = atomicAdd(&cnt[b + d.x], 1);
        r.y = atomicAdd(&cnt[b + d.y], 1);
        r.z = atomicAdd(&cnt[b + d.z], 1);
        r.w = atomicAdd(&cnt[b + d.w], 1);
        *(int4*)&rank[t * E + e4] = r;
    } else {
        for (int e = e4; e < E; ++e)
            rank[t * E + e] = atomicAdd(&cnt[b + dstp[e]], 1);
    }
}

// scan1: per-tile partial sums
__global__ __launch_bounds__(SCAN_BLK) void scan1_kernel(
    const int* __restrict__ cnt, int* __restrict__ bsum, int n)
{
    __shared__ int sh[SCAN_BLK];
    int tid = threadIdx.x;
    int base = blockIdx.x * SCAN_TILE + tid * SCAN_ITEMS;
    int s = 0;
    #pragma unroll
    for (int i = 0; i < SCAN_ITEMS; ++i) {
        int idx = base + i;
        if (idx < n) s += cnt[idx];
    }
    sh[tid] = s; __syncthreads();
    for (int o = SCAN_BLK / 2; o > 0; o >>= 1) {
        if (tid < o) sh[tid] += sh[tid + o];
        __syncthreads();
    }
    if (tid == 0) bsum[blockIdx.x] = sh[0];
}

// scan3 with integrated block-prefix over bsum (offs only)
__global__ __launch_bounds__(SCAN_BLK) void scan3_kernel(
    const int* __restrict__ cnt, const int* __restrict__ bsum,
    int* __restrict__ offs, int n)
{
    __shared__ int red[SCAN_BLK];
    __shared__ int sh[SCAN_BLK];
    const int tid = threadIdx.x;
    int pre = 0;
    for (int i = tid; i < blockIdx.x; i += SCAN_BLK) pre += bsum[i];
    red[tid] = pre; __syncthreads();
    for (int o = SCAN_BLK / 2; o > 0; o >>= 1) {
        if (tid < o) red[tid] += red[tid + o];
        __syncthreads();
    }
    int base0 = red[0];

    int base = blockIdx.x * SCAN_TILE + tid * SCAN_ITEMS;
    int v[SCAN_ITEMS];
    int s = 0;
    #pragma unroll
    for (int i = 0; i < SCAN_ITEMS; ++i) {
        int idx = base + i;
        v[i] = (idx < n) ? cnt[idx] : 0;
        s += v[i];
    }
    sh[tid] = s; __syncthreads();
    for (int o = 1; o < SCAN_BLK; o <<= 1) {
        int t = (tid >= o) ? sh[tid - o] : 0;
        __syncthreads();
        sh[tid] += t;
        __syncthreads();
    }
    int off = base0 + sh[tid] - s;
    #pragma unroll
    for (int i = 0; i < SCAN_ITEMS; ++i) {
        int idx = base + i;
        if (idx < n) {
            offs[idx] = off;
            off += v[i];
            if (idx == n - 1) offs[n] = off;
        }
    }
}

// atomic-free scatter, 4 edges/thread: position = offs[dst] + rank
__global__ __launch_bounds__(256) void scatter_all_kernel(
    EdgeArgs a, const int* __restrict__ offs, const int* __restrict__ rank,
    int* __restrict__ csr_src)
{
    int E = a.E;
    int perE = (E + 3) >> 2;
    int gid = blockIdx.x * 256 + threadIdx.x;
    int t = gid / perE;
    if (t >= 3) return;
    int e4 = (gid - t * perE) * 4;
    const int* dstp = a.dst[t];
    const int* srcp = a.src[t];
    int b = a.base[t];
    if (e4 + 4 <= E) {
        int4 d = *(const int4*)&dstp[e4];
        int4 r = *(const int4*)&rank[t * E + e4];
        int4 s = *(const int4*)&srcp[e4];
        csr_src[offs[b + d.x] + r.x] = s.x;
        csr_src[offs[b + d.y] + r.y] = s.y;
        csr_src[offs[b + d.z] + r.z] = s.z;
        csr_src[offs[b + d.w] + r.w] = s.w;
    } else {
        for (int e = e4; e < E; ++e)
            csr_src[offs[b + dstp[e]] + rank[t * E + e]] = srcp[e];
    }
}

// ---------- fused per-dst softmax + aggregate, 2 lanes per (slot,head), 2-edge unroll ----------
struct AggArgs {
    const unsigned short* K[3];
    const unsigned short* Q[3];
    const unsigned short* V[3];
    const float* pri[3];
    unsigned short* T[3];
};

__global__ __launch_bounds__(256) void csr_agg_all_kernel(
    const int* __restrict__ offs, const int* __restrict__ csr_src,
    AggArgs a, int n_b, int n_a)
{
    int gid = blockIdx.x * 256 + threadIdx.x;
    int si = gid >> 4;
    int hp = gid & 15;
    int h = hp >> 1, p = hp & 1;
    int S = 2 * n_b + n_a;
    if (si >= S) return;
    int s = si;
    int t = (s < n_b) ? 0 : ((s < 2 * n_b) ? 1 : 2);
    int n = s - ((t == 2) ? 2 * n_b : t * n_b);

    const unsigned short *Kp, *Qp, *Vp; const float* prip; unsigned short* Tp;
    if (t == 0)      { Kp=a.K[0]; Qp=a.Q[0]; Vp=a.V[0]; prip=a.pri[0]; Tp=a.T[0]; }
    else if (t == 1) { Kp=a.K[1]; Qp=a.Q[1]; Vp=a.V[1]; prip=a.pri[1]; Tp=a.T[1]; }
    else             { Kp=a.K[2]; Qp=a.Q[2]; Vp=a.V[2]; prip=a.pri[2]; Tp=a.T[2]; }

    int e0 = offs[s], e1 = offs[s + 1];
    const int sub = h * DK + p * 8;

    uint4 q = *(const uint4*)(Qp + (size_t)n * D + sub);
    float qv[8]; unpack8(q, qv);
    float ps = prip[h] * 0.25f;

    float acc[8];
    #pragma unroll
    for (int i = 0; i < 8; ++i) acc[i] = 0.f;
    float den = 0.f;

    int e = e0;
    for (; e + 2 <= e1; e += 2) {
        int s0 = csr_src[e], s1 = csr_src[e + 1];
        uint4 k0 = *(const uint4*)(Kp + (size_t)s0 * D + sub);
        uint4 v0 = *(const uint4*)(Vp + (size_t)s0 * D + sub);
        uint4 k1 = *(const uint4*)(Kp + (size_t)s1 * D + sub);
        uint4 v1 = *(const uint4*)(Vp + (size_t)s1 * D + sub);
        float ka[8], kb[8];
        unpack8(k0, ka); unpack8(k1, kb);
        float d0 = 0.f, d1 = 0.f;
        #pragma unroll
        for (int i = 0; i < 8; ++i) {
            d0 = fmaf(ka[i], qv[i], d0);
            d1 = fmaf(kb[i], qv[i], d1);
        }
        d0 += __shfl_xor(d0, 1, 64);
        d1 += __shfl_xor(d1, 1, 64);
        float ea0 = __expf(d0 * ps);
        float ea1 = __expf(d1 * ps);
        den += ea0 + ea1;
        float va[8], vb[8];
        unpack8(v0, va); unpack8(v1, vb);
        #pragma unroll
        for (int i = 0; i < 8; ++i)
            acc[i] = fmaf(ea0, va[i], fmaf(ea1, vb[i], acc[i]));
    }
    if (e < e1) {
        int s0 = csr_src[e];
        uint4 k = *(const uint4*)(Kp + (size_t)s0 * D + sub);
        uint4 v = *(const uint4*)(Vp + (size_t)s0 * D + sub);
        float kv[8]; unpack8(k, kv);
        float d = 0.f;
        #pragma unroll
        for (int i = 0; i < 8; ++i) d = fmaf(kv[i], qv[i], d);
        d += __shfl_xor(d, 1, 64);
        float ea = __expf(d * ps);
        den += ea;
        float vv[8]; unpack8(v, vv);
        #pragma unroll
        for (int i = 0; i < 8; ++i) acc[i] = fmaf(ea, vv[i], acc[i]);
    }
    float inv = 1.f / fmaxf(den, 1e-9f);
    unsigned short ob[8];
    #pragma unroll
    for (int i = 0; i < 8; ++i) ob[i] = f2bf(acc[i] * inv);
    uint4 o0;
    o0.x = pack2(ob[0], ob[1]);  o0.y = pack2(ob[2], ob[3]);
    o0.z = pack2(ob[4], ob[5]);  o0.w = pack2(ob[6], ob[7]);
    *(uint4*)(Tp + (size_t)n * D + sub) = o0;
}

extern "C" void kernel_launch(void* const* d_in, const int* in_sizes, int n_in,
                              void* d_out, int out_size, void* d_ws, size_t ws_size,
                              hipStream_t stream) {
    const float* x_a = (const float*)d_in[0];
    const float* x_b = (const float*)d_in[1];
    const int* src_ab = (const int*)d_in[2];
    const int* dst_ab = (const int*)d_in[3];
    const int* src_ba = (const int*)d_in[4];
    const int* dst_ba = (const int*)d_in[5];
    const int* src_bb = (const int*)d_in[6];
    const int* dst_bb = (const int*)d_in[7];
    const float* Wk_a = (const float*)d_in[8];  const float* bk_a = (const float*)d_in[9];
    const float* Wq_a = (const float*)d_in[10]; const float* bq_a = (const float*)d_in[11];
    const float* Wv_a = (const float*)d_in[12]; const float* bv_a = (const float*)d_in[13];
    const float* Wa_a = (const float*)d_in[14]; const float* ba_a = (const float*)d_in[15];
    const float* skip_a = (const float*)d_in[16];
    const float* Wk_b = (const float*)d_in[17]; const float* bk_b = (const float*)d_in[18];
    const float* Wq_b = (const float*)d_in[19]; const float* bq_b = (const float*)d_in[20];
    const float* Wv_b = (const float*)d_in[21]; const float* bv_b = (const float*)d_in[22];
    const float* Wa_b = (const float*)d_in[23]; const float* ba_b = (const float*)d_in[24];
    const float* skip_b = (const float*)d_in[25];
    const float* pri_ab = (const float*)d_in[26];
    const float* att_ab = (const float*)d_in[27];
    const float* msg_ab = (const float*)d_in[28];
    const float* pri_ba = (const float*)d_in[29];
    const float* att_ba = (const float*)d_in[30];
    const float* msg_ba = (const float*)d_in[31];
    const float* pri_bb = (const float*)d_in[32];
    const float* att_bb = (const float*)d_in[33];
    const float* msg_bb = (const float*)d_in[34];

    const int n_a = in_sizes[0] / D;
    const int n_b = in_sizes[1] / D;
    const int E = in_sizes[2];
    const int S = 2 * n_b + n_a;

    size_t off = 0;
    char* base = (char*)d_ws;
    auto alloc = [&](size_t bytes) -> void* {
        void* r = base + off;
        off += (bytes + 255) & ~(size_t)255;
        return r;
    };
    unsigned short* k_a = (unsigned short*)alloc((size_t)n_a * D * 2);
    unsigned short* k_b = (unsigned short*)alloc((size_t)n_b * D * 2);
    unsigned short* qab = (unsigned short*)alloc((size_t)n_b * D * 2);
    unsigned short* qbb = (unsigned short*)alloc((size_t)n_b * D * 2);
    unsigned short* qba = (unsigned short*)alloc((size_t)n_a * D * 2);
    unsigned short* vab = (unsigned short*)alloc((size_t)n_a * D * 2);
    unsigned short* vbb = (unsigned short*)alloc((size_t)n_b * D * 2);
    unsigned short* vba = (unsigned short*)alloc((size_t)n_b * D * 2);
    unsigned short* t_a  = (unsigned short*)alloc((size_t)n_a * D * 2);
    unsigned short* t_b1 = (unsigned short*)alloc((size_t)n_b * D * 2);
    unsigned short* t_b2 = (unsigned short*)alloc((size_t)n_b * D * 2);
    int* cnt    = (int*)alloc((size_t)S * 4);
    int* offs   = (int*)alloc(((size_t)S + 1) * 4);
    int* rank   = (int*)alloc((size_t)3 * E * 4);
    int* csr_src= (int*)alloc((size_t)3 * E * 4);
    int* bsum   = (int*)alloc(256 * 4);
    unsigned short* wt_plain[4];
    for (int i = 0; i < 4; ++i) wt_plain[i] = (unsigned short*)alloc((size_t)D * D * 2);
    unsigned short* wt_fold[6];
    float* bf_fold[6];
    for (int i = 0; i < 6; ++i) {
        wt_fold[i] = (unsigned short*)alloc((size_t)D * D * 2);
        bf_fold[i] = (float*)alloc((size_t)D * 4);
    }

    // prep: transposes (Wk_a, Wk_b, Wa_a, Wa_b), folds, zero cnt
    WTIn win; WTOut wout;
    const float* worig[4] = {Wk_a, Wk_b, Wa_a, Wa_b};
    for (int i = 0; i < 4; ++i) { win.w[i] = worig[i]; wout.wt[i] = wt_plain[i]; }
    FoldArgs fa;
    const float* fW[6] = {Wq_b, Wq_b, Wq_a, Wv_a, Wv_b, Wv_b};
    const float* fR[6] = {att_ab, att_bb, att_ba, msg_ab, msg_bb, msg_ba};
    const float* fb[6] = {bq_b, bq_b, bq_a, bv_a, bv_b, bv_b};
    int fm[6] = {0, 0, 0, 1, 1, 1};
    for (int i = 0; i < 6; ++i) {
        fa.W[i] = fW[i]; fa.R[i] = fR[i]; fa.b[i] = fb[i];
        fa.WT[i] = wt_fold[i]; fa.bf[i] = bf_fold[i]; fa.mode[i] = fm[i];
    }
    int nz = (S + 1023) / 1024;
    prep_kernel<<<112 + nz, 256, 0, stream>>>(win, wout, fa, cnt, S);

    // combined CSR build (rank-in-hist vec4, two-kernel scan, atomic-free scatter vec4)
    EdgeArgs ea;
    ea.src[0] = src_ab; ea.dst[0] = dst_ab;
    ea.src[1] = src_bb; ea.dst[1] = dst_bb;
    ea.src[2] = src_ba; ea.dst[2] = dst_ba;
    ea.base[0] = 0; ea.base[1] = n_b; ea.base[2] = 2 * n_b;
    ea.E = E;
    int perE = (E + 3) >> 2;
    int gv = (3 * perE + 255) / 256;
    hist_all_kernel<<<gv, 256, 0, stream>>>(ea, cnt, rank);
    int nb = (S + SCAN_TILE - 1) / SCAN_TILE;
    scan1_kernel<<<nb, SCAN_BLK, 0, stream>>>(cnt, bsum, S);
    scan3_kernel<<<nb, SCAN_BLK, 0, stream>>>(cnt, bsum, offs, S);
    scatter_all_kernel<<<gv, 256, 0, stream>>>(ea, offs, rank, csr_src);

    // fused projections (both node types)
    const int gb_a = (n_a + 63) / 64;
    const int gb_b = (n_b + 63) / 64;
    ProjFusedArgs pa;
    pa.X[0] = x_a; pa.N[0] = n_a; pa.nmat[0] = 3;
    pa.X[1] = x_b; pa.N[1] = n_b; pa.nmat[1] = 5;
    pa.nblk0 = gb_a;
    pa.wt[0][0] = wt_plain[0]; pa.bias[0][0] = bk_a;       pa.out[0][0] = k_a;
    pa.wt[0][1] = wt_fold[2];  pa.bias[0][1] = bf_fold[2]; pa.out[0][1] = qba;
    pa.wt[0][2] = wt_fold[3];  pa.bias[0][2] = bf_fold[3]; pa.out[0][2] = vab;
    pa.wt[0][3] = wt_plain[0]; pa.bias[0][3] = bk_a;       pa.out[0][3] = k_a;   // unused
    pa.wt[0][4] = wt_plain[0]; pa.bias[0][4] = bk_a;       pa.out[0][4] = k_a;   // unused
    pa.wt[1][0] = wt_plain[1]; pa.bias[1][0] = bk_b;       pa.out[1][0] = k_b;
    pa.wt[1][1] = wt_fold[0];  pa.bias[1][1] = bf_fold[0]; pa.out[1][1] = qab;
    pa.wt[1][2] = wt_fold[1];  pa.bias[1][2] = bf_fold[1]; pa.out[1][2] = qbb;
    pa.wt[1][3] = wt_fold[4];  pa.bias[1][3] = bf_fold[4]; pa.out[1][3] = vbb;
    pa.wt[1][4] = wt_fold[5];  pa.bias[1][4] = bf_fold[5]; pa.out[1][4] = vba;
    proj_fused_kernel<<<gb_a + gb_b, 256, 0, stream>>>(pa);

    // fused aggregate (all etypes, natural slot order, 2 lanes/head, 2-edge unroll)
    AggArgs aa;
    aa.K[0] = k_a; aa.Q[0] = qab; aa.V[0] = vab; aa.pri[0] = pri_ab; aa.T[0] = t_b1;
    aa.K[1] = k_b; aa.Q[1] = qbb; aa.V[1] = vbb; aa.pri[1] = pri_bb; aa.T[1] = t_b2;
    aa.K[2] = k_b; aa.Q[2] = qba; aa.V[2] = vba; aa.pri[2] = pri_ba; aa.T[2] = t_a;
    int gs = (S * 16 + 255) / 256;
    csr_agg_all_kernel<<<gs, 256, 0, stream>>>(offs, csr_src, aa, n_b, n_a);

    // fused final skip-connection GEMMs
    float* out_a = (float*)d_out;
    float* out_b = (float*)d_out + (size_t)n_a * D;
    OutFusedArgs oa;
    oa.T1[0] = t_a;  oa.T2[0] = t_a;  oa.WT[0] = wt_plain[2]; oa.bias[0] = ba_a;
    oa.skip[0] = skip_a; oa.X[0] = x_a; oa.O[0] = out_a; oa.N[0] = n_a; oa.nsrc[0] = 1;
    oa.T1[1] = t_b1; oa.T2[1] = t_b2; oa.WT[1] = wt_plain[3]; oa.bias[1] = ba_b;
    oa.skip[1] = skip_b; oa.X[1] = x_b; oa.O[1] = out_b; oa.N[1] = n_b; oa.nsrc[1] = 2;
    oa.nblk0 = gb_a;
    out_fused_kernel<<<gb_a + gb_b, 256, 0, stream>>>(oa);
}